// Round 5
// baseline (556.696 us; speedup 1.0000x reference)
//
#include <hip/hip_runtime.h>
#include <hip/hip_bf16.h>

// ---- problem constants ----
constexpr int B   = 8;
constexpr int CIN = 66;
constexpr int H   = 128, W = 128;
constexpr int C1  = 256;
constexpr int NP  = 128;
constexpr int V   = 128;
constexpr int SD  = 128;
constexpr int NRES = 7;
constexpr float RO = 4.0f;

typedef __bf16 bf16x8 __attribute__((ext_vector_type(8)));
typedef float  f32x4  __attribute__((ext_vector_type(4)));
typedef unsigned short u16x8 __attribute__((ext_vector_type(8)));

__device__ inline float bfu2f(unsigned short u) {
    union { unsigned int i; float f; } c; c.i = ((unsigned)u) << 16; return c.f;
}

// ===================== K0a: pack x -> channel-last bf16 with borders =====================
__global__ __launch_bounds__(256) void k_pack_x(const float* __restrict__ x,
                                                __hip_bfloat16* __restrict__ xp)
{
    const int bi  = blockIdx.x;          // 8*130
    const int b   = bi / 130;
    const int yp  = bi % 130;
    const int tid = threadIdx.x;
    const int y   = yp - 1;
    const bool interior = (y >= 0 && y < H);

    __shared__ float xs[CIN * W];
    if (interior) {
        for (int i = tid; i < CIN * W; i += 256)
            xs[i] = x[((size_t)b * CIN + (i >> 7)) * (H * W) + y * W + (i & 127)];
    }
    __syncthreads();
    __hip_bfloat16* op = xp + ((size_t)b * 130 + yp) * (130 * 72);
    for (int i = tid; i < 130 * 72; i += 256) {
        int xpx = i / 72, c = i - xpx * 72;
        int xx = xpx - 1;
        float v = 0.f;
        if (interior && xx >= 0 && xx < W && c < CIN) v = xs[c * W + xx];
        op[i] = __float2bfloat16(v);
    }
}

// ===================== K0b: ALL weight packs in one launch =====================
// blocks [0,256): conv3x3 w -> wp2 [3 ky][4 ocg][64 oc][232]
// blocks [256,1280): snake  -> wpk2 [8 l][9 k][128 oc][128 ic]
// blocks [1280,1536): fw    -> fwb  [256][1024]
// blocks [1536,1792): ppw1[:,256:] -> pw1hb [256][1024]
// blocks [1792,1856): ppw2  -> pw2b [64][256]
__global__ __launch_bounds__(256) void k_pack_weights(
    const float* __restrict__ w3, const float* __restrict__ hw,
    const float* __restrict__ rw, const float* __restrict__ fw,
    const float* __restrict__ ppw1, const float* __restrict__ ppw2,
    __hip_bfloat16* __restrict__ wp2, __hip_bfloat16* __restrict__ wpk2,
    __hip_bfloat16* __restrict__ fwb, __hip_bfloat16* __restrict__ pw1hb,
    __hip_bfloat16* __restrict__ pw2b)
{
    const int bid = blockIdx.x, tid = threadIdx.x;
    if (bid < 256) {
        int oc = bid, ocg = bid >> 6, ocl = bid & 63;
        for (int t = tid; t < 3 * 232; t += 256) {
            int ky = t / 232, s = t - ky * 232;
            float v = 0.f;
            if (s < 216) {
                int kx = s / 72, ic = s - kx * 72;
                if (ic < CIN) v = w3[((size_t)(oc * CIN + ic) * 3 + ky) * 3 + kx];
            }
            wp2[(((size_t)ky * 4 + ocg) * 64 + ocl) * 232 + s] = __float2bfloat16(v);
        }
    } else if (bid < 1280) {
        int q = bid - 256, l = q >> 7, oc = q & 127;
        for (int t = tid; t < 9 * 128; t += 256) {
            int k = t >> 7, ic = t & 127;
            float v = 0.f;
            if (l == 0) { if (ic < 66) v = hw[((size_t)oc * 66 + ic) * 9 + k]; }
            else v = rw[((((size_t)(l - 1) * 128 + oc) * 128) + ic) * 9 + k];
            wpk2[(((size_t)l * 9 + k) * 128 + oc) * 128 + ic] = __float2bfloat16(v);
        }
    } else if (bid < 1536) {
        int r = bid - 1280;
        for (int c = tid; c < 1024; c += 256)
            fwb[(size_t)r * 1024 + c] = __float2bfloat16(fw[(size_t)r * 1024 + c]);
    } else if (bid < 1792) {
        int r = bid - 1536;
        for (int c = tid; c < 1024; c += 256)
            pw1hb[(size_t)r * 1024 + c] = __float2bfloat16(ppw1[(size_t)r * 1280 + 256 + c]);
    } else {
        int r = bid - 1792;
        for (int c = tid; c < 256; c += 256)
            pw2b[(size_t)r * 256 + c] = __float2bfloat16(ppw2[(size_t)r * 256 + c]);
    }
}

// ===================== K1: 3x3 conv, 2-phase pipelined implicit-GEMM =====================
// grid (1024 = b*128+y, 4 ocg), block 256 = 4 waves (2M x 2N), wave 64 pos x 32 oc.
// A: 3 padded rows staged once (56160 B). B: per-ky 29696 B tiles, double-buffered;
// prefetch of B(ky+1) issued BEFORE compute(ky); one barrier per phase.
__global__ __launch_bounds__(256) void k_conv3x3_mfma(
    const __hip_bfloat16* __restrict__ xp,   // [8][130][130][72]
    const __hip_bfloat16* __restrict__ wp2,  // [3][4][64][232]
    const float* __restrict__ bias,
    __hip_bfloat16* __restrict__ out)        // [8][128 y][128 x][256 oc]
{
    __shared__ __hip_bfloat16 ash[28112];        // 3*9360 + 32 pad
    __shared__ __hip_bfloat16 bsh[2 * 14848];    // 2 x 64*232

    const int tid = threadIdx.x;
    const int ln  = tid & 63;
    const int wv  = tid >> 6;
    const int wm  = (wv >> 1) * 64;
    const int wn  = (wv & 1) * 32;
    const int l15 = ln & 15;
    const int lhi = ln >> 4;

    const int by  = blockIdx.x;
    const int b   = by >> 7;
    const int y   = by & 127;
    const int ocg = blockIdx.y;
    const int ocb = ocg * 64;

    // prologue: stage A (3 rows) + B(ky=0)
    {
        const char* g = (const char*)(xp + ((size_t)b * 130 + y) * 9360);
        for (int off = tid * 16; off < 56160; off += 4096)
            __builtin_amdgcn_global_load_lds(
                (const __attribute__((address_space(1))) void*)(g + off),
                (__attribute__((address_space(3))) void*)((char*)ash + off), 16, 0, 0);
        const char* gb = (const char*)(wp2 + ((size_t)0 * 4 + ocg) * 14848);
        for (int off = tid * 16; off < 29696; off += 4096)
            __builtin_amdgcn_global_load_lds(
                (const __attribute__((address_space(1))) void*)(gb + off),
                (__attribute__((address_space(3))) void*)((char*)bsh + off), 16, 0, 0);
        if (tid < 32) ash[28080 + tid] = __float2bfloat16(0.f);  // zero overread tail
    }
    __syncthreads();

    f32x4 acc[4][2] = {};
#pragma unroll
    for (int ky = 0; ky < 3; ++ky) {
        // prefetch next B tile into other buffer (flies under the MFMAs below)
        if (ky < 2) {
            const char* gb = (const char*)(wp2 + ((size_t)(ky + 1) * 4 + ocg) * 14848);
            char* dst = (char*)bsh + ((ky + 1) & 1) * 29696;
            for (int off = tid * 16; off < 29696; off += 4096)
                __builtin_amdgcn_global_load_lds(
                    (const __attribute__((address_space(1))) void*)(gb + off),
                    (__attribute__((address_space(3))) void*)(dst + off), 16, 0, 0);
        }
        const char* arow = (const char*)ash + ky * 18720;
        const char* bb   = (const char*)bsh + (ky & 1) * 29696;
#pragma unroll
        for (int ks = 0; ks < 7; ++ks) {
            bf16x8 a[4], bq[2];
#pragma unroll
            for (int m = 0; m < 4; ++m)
                a[m] = *(const bf16x8*)(arow + (wm + m * 16 + l15) * 144 + ks * 64 + lhi * 16);
#pragma unroll
            for (int n = 0; n < 2; ++n)
                bq[n] = *(const bf16x8*)(bb + (wn + n * 16 + l15) * 464 + ks * 64 + lhi * 16);
#pragma unroll
            for (int m = 0; m < 4; ++m)
#pragma unroll
                for (int n = 0; n < 2; ++n)
                    acc[m][n] = __builtin_amdgcn_mfma_f32_16x16x32_bf16(
                        a[m], bq[n], acc[m][n], 0, 0, 0);
        }
        __syncthreads();
    }

    // epilogue: bias + relu -> channel-last bf16
#pragma unroll
    for (int n = 0; n < 2; ++n) {
        int oc = ocb + wn + n * 16 + l15;
        float bb = bias[oc];
#pragma unroll
        for (int m = 0; m < 4; ++m) {
#pragma unroll
            for (int r = 0; r < 4; ++r) {
                int pos = wm + m * 16 + lhi * 4 + r;
                float v = acc[m][n][r] + bb;
                v = v > 0.f ? v : 0.f;
                out[(((size_t)b * 128 + y) * 128 + pos) * 256 + oc] = __float2bfloat16(v);
            }
        }
    }
}

// ===================== K2: 1x1 conv (256 -> 64) MFMA =====================
__global__ __launch_bounds__(256) void k_conv1x1_mfma(
    const __hip_bfloat16* __restrict__ feat1,   // [131072 pos][256]
    const __hip_bfloat16* __restrict__ w2b,     // [64][256]
    const float* __restrict__ b2,
    __hip_bfloat16* __restrict__ feat2)         // [131072 pos][64]
{
    const int tid = threadIdx.x;
    const int ln  = tid & 63;
    const int wv  = tid >> 6;
    const int wm  = wv * 64;
    const int l15 = ln & 15;
    const int lhi = ln >> 4;
    const int pos0 = blockIdx.x * 256;

    __shared__ __hip_bfloat16 wsh[64 * 136];
    for (int i = tid; i < 1024; i += 256) {
        int row = i >> 4, slot = i & 15;
        *(bf16x8*)&wsh[row * 136 + slot * 8] = *(const bf16x8*)(w2b + row * 256 + slot * 8);
    }
    __syncthreads();

    f32x4 acc[4][4] = {};
#pragma unroll
    for (int kk = 0; kk < 8; ++kk) {
        bf16x8 a[4], bq[4];
#pragma unroll
        for (int m = 0; m < 4; ++m)
            a[m] = *(const bf16x8*)(feat1 + (size_t)(pos0 + wm + m * 16 + l15) * 256 + kk * 32 + lhi * 8);
#pragma unroll
        for (int n = 0; n < 4; ++n)
            bq[n] = *(const bf16x8*)&wsh[(n * 16 + l15) * 136 + kk * 32 + lhi * 8];
#pragma unroll
        for (int m = 0; m < 4; ++m)
#pragma unroll
            for (int n = 0; n < 4; ++n)
                acc[m][n] = __builtin_amdgcn_mfma_f32_16x16x32_bf16(a[m], bq[n], acc[m][n], 0, 0, 0);
    }
#pragma unroll
    for (int n = 0; n < 4; ++n) {
        int og = n * 16 + l15;
        float bb = b2[og];
#pragma unroll
        for (int m = 0; m < 4; ++m)
#pragma unroll
            for (int r = 0; r < 4; ++r) {
                int pos = pos0 + wm + m * 16 + lhi * 4 + r;
                feat2[(size_t)pos * 64 + og] = __float2bfloat16(acc[m][n][r] + bb);
            }
    }
}

// ===================== K3: bilinear sample + coords -> X0 [p][v][128] bf16 =====================
__global__ __launch_bounds__(256) void k_sample(
    const __hip_bfloat16* __restrict__ feat2, const float* __restrict__ ipoly,
    const float* __restrict__ cpoly, const int* __restrict__ ind,
    __hip_bfloat16* __restrict__ X0)
{
    const int p = blockIdx.x;
    const int v = threadIdx.x & 127;
    const int half = threadIdx.x >> 7;

    float px = ipoly[(p * V + v) * 2 + 0];
    float py = ipoly[(p * V + v) * 2 + 1];
    float ix = px - 0.5f, iy = py - 0.5f;
    float x0f = floorf(ix), y0f = floorf(iy);
    float wx = ix - x0f, wy = iy - y0f;
    int x0 = (int)x0f, y0 = (int)y0f;

    int   xsv[2] = {x0, x0 + 1}, ysv[2] = {y0, y0 + 1};
    float wxs[2] = {1.f - wx, wx}, wys[2] = {1.f - wy, wy};
    float cw[4]; int cbase[4];
#pragma unroll
    for (int jy = 0; jy < 2; ++jy)
#pragma unroll
        for (int jx = 0; jx < 2; ++jx) {
            int xi = xsv[jx], yi = ysv[jy];
            bool ok = (xi >= 0) && (xi < W) && (yi >= 0) && (yi < H);
            int xc = min(max(xi, 0), W - 1);
            int yc = min(max(yi, 0), H - 1);
            cw[jy * 2 + jx]    = wys[jy] * wxs[jx] * (ok ? 1.f : 0.f);
            cbase[jy * 2 + jx] = yc * W + xc;
        }

    const __hip_bfloat16* fb = feat2 + (size_t)ind[p] * (16384 * 64);
    __hip_bfloat16* xr = X0 + ((size_t)p * V + v) * 128;
#pragma unroll
    for (int ch = 0; ch < 4; ++ch) {
        int chh = half * 4 + ch;
        float s[8];
#pragma unroll
        for (int e = 0; e < 8; ++e) s[e] = 0.f;
#pragma unroll
        for (int j = 0; j < 4; ++j) {
            u16x8 t = *(const u16x8*)(fb + (size_t)cbase[j] * 64 + chh * 8);
#pragma unroll
            for (int e = 0; e < 8; ++e) s[e] += cw[j] * bfu2f(t[e]);
        }
#pragma unroll
        for (int e = 0; e < 8; ++e) xr[chh * 8 + e] = __float2bfloat16(s[e]);
    }
    if (half) {
        xr[64] = __float2bfloat16(cpoly[(p * V + v) * 2 + 0] * RO);
        xr[65] = __float2bfloat16(cpoly[(p * V + v) * 2 + 1] * RO);
        for (int c = 66; c < 128; ++c) xr[c] = __float2bfloat16(0.f);
    }
}

// ===================== K4: snake circular conv layer (MFMA, halo-window) =====================
// grid (NP, 4): blockIdx.y = mg*2+og ; block 64 pos x 64 oc ; 4 waves 2x2 (32x32 each).
// x staged with circular halo (96 rows) -> no modulo in inner loop; 2 blocks/CU.
__global__ __launch_bounds__(256) void k_snake_mfma(
    const __hip_bfloat16* __restrict__ xin,   // [NP][V][128]
    const __hip_bfloat16* __restrict__ wl,    // [9][128 oc][128 ic]
    const float* __restrict__ bias, const float* __restrict__ gamma,
    const float* __restrict__ beta,
    const __hip_bfloat16* __restrict__ resin, // nullable, [NP][V][128]
    __hip_bfloat16* __restrict__ out,         // [NP][V][128]
    int dil)
{
    const int tid = threadIdx.x;
    const int ln  = tid & 63;
    const int wv  = tid >> 6;
    const int wm  = (wv >> 1) * 32;
    const int wn  = (wv & 1) * 32;
    const int l15 = ln & 15;
    const int lhi = ln >> 4;
    const int p   = blockIdx.x;
    const int mg  = blockIdx.y >> 1;
    const int og  = blockIdx.y & 1;
    const int pos0 = mg * 64;
    const int ocb  = og * 64;

    __shared__ __hip_bfloat16 xs[96 * 136];
    const __hip_bfloat16* xb = xin + (size_t)p * (V * 128);
    for (int i = tid; i < 96 * 16; i += 256) {
        int r = i >> 4, slot = i & 15;
        int grow = (pos0 - 16 + r) & 127;
        *(bf16x8*)&xs[r * 136 + slot * 8] = *(const bf16x8*)(xb + (size_t)grow * 128 + slot * 8);
    }
    __syncthreads();

    f32x4 acc[2][2] = {};
#pragma unroll 1
    for (int k = 0; k < 9; ++k) {
        const int ofs = (k - 4) * dil + 16;
        const __hip_bfloat16* wk = wl + (size_t)k * (128 * 128);
#pragma unroll
        for (int kc = 0; kc < 4; ++kc) {
            bf16x8 a[2], bq[2];
#pragma unroll
            for (int m = 0; m < 2; ++m) {
                int row = wm + m * 16 + l15 + ofs;
                a[m] = *(const bf16x8*)&xs[row * 136 + kc * 32 + lhi * 8];
            }
#pragma unroll
            for (int n = 0; n < 2; ++n)
                bq[n] = *(const bf16x8*)(wk + (size_t)(ocb + wn + n * 16 + l15) * 128 + kc * 32 + lhi * 8);
#pragma unroll
            for (int m = 0; m < 2; ++m)
#pragma unroll
                for (int n = 0; n < 2; ++n)
                    acc[m][n] = __builtin_amdgcn_mfma_f32_16x16x32_bf16(a[m], bq[n], acc[m][n], 0, 0, 0);
        }
    }

#pragma unroll
    for (int n = 0; n < 2; ++n) {
        int oc = ocb + wn + n * 16 + l15;
        float bb = bias[oc], gg = gamma[oc], bt = beta[oc];
#pragma unroll
        for (int m = 0; m < 2; ++m)
#pragma unroll
            for (int r = 0; r < 4; ++r) {
                int pos = pos0 + wm + m * 16 + lhi * 4 + r;
                size_t idx = ((size_t)p * V + pos) * 128 + oc;
                float v = acc[m][n][r] + bb;
                v = v > 0.f ? v : 0.f;
                v = v * gg + bt;
                if (resin) v += __bfloat162float(resin[idx]);
                out[idx] = __float2bfloat16(v);
            }
    }
}

// ===================== K5: vconv over concat states (K=1024, O=256) =====================
__global__ __launch_bounds__(256) void k_vconv1024(
    const __hip_bfloat16* __restrict__ xin,   // states [8][NP][V][128]
    const __hip_bfloat16* __restrict__ wb,    // [256][1024]
    const float* __restrict__ fbias,          // nullable [256]
    const float* __restrict__ pbias,          // nullable [NP][256]
    int relu,
    __hip_bfloat16* __restrict__ out)         // [NP][V][256]
{
    const int tid = threadIdx.x;
    const int ln  = tid & 63;
    const int wv  = tid >> 6;
    const int wm  = (wv >> 1) * 64;
    const int wn  = (wv & 1) * 64;
    const int l15 = ln & 15;
    const int lhi = ln >> 4;
    const int p   = blockIdx.x;
    const int ocb = blockIdx.y * 128;

    f32x4 acc[4][4] = {};
    for (int s = 0; s < 8; ++s) {
        const __hip_bfloat16* xa = xin + ((size_t)s * NP + p) * (V * 128);
#pragma unroll
        for (int kc = 0; kc < 4; ++kc) {
            bf16x8 a[4], bq[4];
#pragma unroll
            for (int m = 0; m < 4; ++m)
                a[m] = *(const bf16x8*)(xa + (size_t)(wm + m * 16 + l15) * 128 + kc * 32 + lhi * 8);
#pragma unroll
            for (int n = 0; n < 4; ++n)
                bq[n] = *(const bf16x8*)(wb + (size_t)(ocb + wn + n * 16 + l15) * 1024 + s * 128 + kc * 32 + lhi * 8);
#pragma unroll
            for (int m = 0; m < 4; ++m)
#pragma unroll
                for (int n = 0; n < 4; ++n)
                    acc[m][n] = __builtin_amdgcn_mfma_f32_16x16x32_bf16(a[m], bq[n], acc[m][n], 0, 0, 0);
        }
    }
#pragma unroll
    for (int n = 0; n < 4; ++n) {
        int og = ocb + wn + n * 16 + l15;
        float bb = (fbias ? fbias[og] : 0.f) + (pbias ? pbias[(size_t)p * 256 + og] : 0.f);
#pragma unroll
        for (int m = 0; m < 4; ++m)
#pragma unroll
            for (int r = 0; r < 4; ++r) {
                int pos = wm + m * 16 + lhi * 4 + r;
                float v = acc[m][n][r] + bb;
                if (relu) v = v > 0.f ? v : 0.f;
                out[((size_t)p * V + pos) * 256 + og] = __float2bfloat16(v);
            }
    }
}

// ===================== K6: h2 = relu(pw2 @ h1 + pb2)  (K=256, O=64) =====================
__global__ __launch_bounds__(128) void k_h2(
    const __hip_bfloat16* __restrict__ h1,    // [NP][V][256]
    const __hip_bfloat16* __restrict__ w2b,   // [64][256]
    const float* __restrict__ pb2,
    __hip_bfloat16* __restrict__ h2)          // [NP][V][64]
{
    const int tid = threadIdx.x;
    const int ln  = tid & 63;
    const int wv  = tid >> 6;
    const int wm  = wv * 64;
    const int l15 = ln & 15;
    const int lhi = ln >> 4;
    const int p   = blockIdx.x;

    f32x4 acc[4][4] = {};
#pragma unroll
    for (int kk = 0; kk < 8; ++kk) {
        bf16x8 a[4], bq[4];
#pragma unroll
        for (int m = 0; m < 4; ++m)
            a[m] = *(const bf16x8*)(h1 + ((size_t)p * V + wm + m * 16 + l15) * 256 + kk * 32 + lhi * 8);
#pragma unroll
        for (int n = 0; n < 4; ++n)
            bq[n] = *(const bf16x8*)(w2b + (size_t)(n * 16 + l15) * 256 + kk * 32 + lhi * 8);
#pragma unroll
        for (int m = 0; m < 4; ++m)
#pragma unroll
            for (int n = 0; n < 4; ++n)
                acc[m][n] = __builtin_amdgcn_mfma_f32_16x16x32_bf16(a[m], bq[n], acc[m][n], 0, 0, 0);
    }
#pragma unroll
    for (int n = 0; n < 4; ++n) {
        int og = n * 16 + l15;
        float bb = pb2[og];
#pragma unroll
        for (int m = 0; m < 4; ++m)
#pragma unroll
            for (int r = 0; r < 4; ++r) {
                int pos = wm + m * 16 + lhi * 4 + r;
                float v = acc[m][n][r] + bb;
                v = v > 0.f ? v : 0.f;
                h2[((size_t)p * V + pos) * 64 + og] = __float2bfloat16(v);
            }
    }
}

// ===================== K7: fused g = max_v(fused), gc = pb1 + pw1[:, :256] . g =====================
__global__ __launch_bounds__(256) void k_gmaxgc(const __hip_bfloat16* __restrict__ fused,
                                                const float* __restrict__ pw1,
                                                const float* __restrict__ pb1,
                                                float* __restrict__ gc)
{
    int p = blockIdx.x, o = threadIdx.x;
    float m = -3.4e38f;
    for (int v = 0; v < V; ++v)
        m = fmaxf(m, __bfloat162float(fused[((size_t)p * V + v) * 256 + o]));
    __shared__ float gl[256];
    gl[o] = m;
    __syncthreads();
    float a = pb1[o];
    const float* wr = pw1 + (size_t)o * 1280;
    for (int c = 0; c < 256; ++c) a += wr[c] * gl[c];
    gc[(size_t)p * 256 + o] = a;
}

// ===================== K8: final pw3 + compose output =====================
__global__ __launch_bounds__(128) void k_final(const __hip_bfloat16* __restrict__ h2,
                                               const float* __restrict__ pw3,
                                               const float* __restrict__ pb3,
                                               const float* __restrict__ ipoly,
                                               float* __restrict__ outp)
{
    int p = blockIdx.x, v = threadIdx.x;
    __shared__ float w3[128];
    w3[v] = pw3[v];
    __syncthreads();
    float a0 = pb3[0], a1 = pb3[1];
    const u16x8* hp = (const u16x8*)(h2 + ((size_t)p * V + v) * 64);
#pragma unroll
    for (int ch = 0; ch < 8; ++ch) {
        u16x8 t = hp[ch];
#pragma unroll
        for (int e = 0; e < 8; ++e) {
            int c = ch * 8 + e;
            float hv = bfu2f(t[e]);
            a0 += w3[c] * hv;
            a1 += w3[64 + c] * hv;
        }
    }
    int idx = (p * V + v) * 2;
    outp[idx]     = ipoly[idx] * RO + a0;
    outp[idx + 1] = ipoly[idx + 1] * RO + a1;
}

// ===================== host =====================
extern "C" void kernel_launch(void* const* d_in, const int* in_sizes, int n_in,
                              void* d_out, int out_size, void* d_ws, size_t ws_size,
                              hipStream_t stream)
{
    const float* cnn   = (const float*)d_in[0];
    const float* ipoly = (const float*)d_in[1];
    const float* cpoly = (const float*)d_in[2];
    const int*   ind   = (const int*)d_in[3];
    const float* pw1c  = (const float*)d_in[4];
    const float* pb1c  = (const float*)d_in[5];
    const float* pw2c  = (const float*)d_in[6];
    const float* pb2c  = (const float*)d_in[7];
    const float* hw    = (const float*)d_in[8];
    const float* hb    = (const float*)d_in[9];
    const float* hg    = (const float*)d_in[10];
    const float* hbt   = (const float*)d_in[11];
    const float* rw    = (const float*)d_in[12];
    const float* rb    = (const float*)d_in[13];
    const float* rg    = (const float*)d_in[14];
    const float* rbt   = (const float*)d_in[15];
    const float* fw    = (const float*)d_in[16];
    const float* fb    = (const float*)d_in[17];
    const float* ppw1  = (const float*)d_in[18];
    const float* ppb1  = (const float*)d_in[19];
    const float* ppw2  = (const float*)d_in[20];
    const float* ppb2  = (const float*)d_in[21];
    const float* ppw3  = (const float*)d_in[22];
    const float* ppb3  = (const float*)d_in[23];
    float* outp = (float*)d_out;

    char* ws = (char*)d_ws;
    // layout (time-aliased):
    //  [0,64M): feat1 [131072][256] bf16 -> later states/fused/h1/h2/gc
    //  [64M+3M..): xp -> later feat2 [131072][64] bf16
    //  tail: wp2, wpk2, fwb, pw1hb, pw2b, X0
    __hip_bfloat16* feat1  = (__hip_bfloat16*)(ws);
    __hip_bfloat16* states = (__hip_bfloat16*)(ws);
    __hip_bfloat16* fused  = (__hip_bfloat16*)(ws + 33554432);
    __hip_bfloat16* h1     = (__hip_bfloat16*)(ws + 41943040);
    __hip_bfloat16* h2     = (__hip_bfloat16*)(ws + 50331648);
    float*          gcbuf  = (float*)(ws + 52428800);
    __hip_bfloat16* xp     = (__hip_bfloat16*)(ws + 67108864);
    __hip_bfloat16* feat2  = (__hip_bfloat16*)(ws + 67108864);
    __hip_bfloat16* wp2    = (__hip_bfloat16*)(ws + 86577664);
    __hip_bfloat16* wpk2   = (__hip_bfloat16*)(ws + 86934016);
    __hip_bfloat16* fwb    = (__hip_bfloat16*)(ws + 89293312);
    __hip_bfloat16* pw1hb  = (__hip_bfloat16*)(ws + 89817600);
    __hip_bfloat16* pw2b   = (__hip_bfloat16*)(ws + 90341888);
    __hip_bfloat16* X0     = (__hip_bfloat16*)(ws + 90374656);

    // 0) packs (2 launches)
    k_pack_x<<<dim3(8 * 130), 256, 0, stream>>>(cnn, xp);
    k_pack_weights<<<dim3(1856), 256, 0, stream>>>(pw1c, hw, rw, fw, ppw1, ppw2,
                                                   wp2, wpk2, fwb, pw1hb, pw2b);

    // 1) 3x3 conv + relu -> feat1 (channel-last bf16), 2-phase pipelined
    k_conv3x3_mfma<<<dim3(1024, 4), 256, 0, stream>>>(xp, wp2, pb1c, feat1);
    // 2) 1x1 conv -> feat2 (channel-last bf16)
    k_conv1x1_mfma<<<dim3(512), 256, 0, stream>>>(feat1, pw2b, pb2c, feat2);
    // 3) bilinear sample + coords -> X0 [p][v][128] bf16
    k_sample<<<dim3(NP), 256, 0, stream>>>(feat2, ipoly, cpoly, ind, X0);

    // 4) head conv -> states[0]
    k_snake_mfma<<<dim3(NP, 4), 256, 0, stream>>>(X0, wpk2, hb, hg, hbt, nullptr,
                                                  states, 1);
    // 5..11) residual dilated convs
    const int dil[NRES] = {1, 1, 1, 2, 2, 4, 4};
    const size_t SSZ = (size_t)NP * V * 128;
    for (int i = 0; i < NRES; ++i) {
        const __hip_bfloat16* xin = states + (size_t)i * SSZ;
        __hip_bfloat16* yout      = states + (size_t)(i + 1) * SSZ;
        const __hip_bfloat16* wi  = wpk2 + (size_t)(i + 1) * 9 * 128 * 128;
        k_snake_mfma<<<dim3(NP, 4), 256, 0, stream>>>(xin, wi, rb + i * SD, rg + i * SD,
                                                      rbt + i * SD, xin, yout, dil[i]);
    }

    // 12) fused 1x1 over concat states -> fused [p][v][256]
    k_vconv1024<<<dim3(NP, 2), 256, 0, stream>>>(states, fwb, fb, nullptr, 0, fused);
    // 13+14) g = max over vertices ; gc = pb1 + pw1[:, :256] @ g
    k_gmaxgc<<<dim3(NP), 256, 0, stream>>>(fused, ppw1, ppb1, gcbuf);
    // 15) h1 = relu(pw1[:, 256:] @ state + gc)
    k_vconv1024<<<dim3(NP, 2), 256, 0, stream>>>(states, pw1hb, nullptr, gcbuf, 1, h1);
    // 16) h2 = relu(pw2 @ h1 + pb2)
    k_h2<<<dim3(NP), 128, 0, stream>>>(h1, pw2b, ppb2, h2);
    // 17) final
    k_final<<<dim3(NP), 128, 0, stream>>>(h2, ppw3, ppb3, ipoly, outp);
}

// Round 6
// 453.104 us; speedup vs baseline: 1.2286x; 1.2286x over previous
//
#include <hip/hip_runtime.h>
#include <hip/hip_bf16.h>

// ---- problem constants ----
constexpr int B   = 8;
constexpr int CIN = 66;
constexpr int H   = 128, W = 128;
constexpr int C1  = 256;
constexpr int NP  = 128;
constexpr int V   = 128;
constexpr int SD  = 128;
constexpr int NRES = 7;
constexpr float RO = 4.0f;

typedef __bf16 bf16x8 __attribute__((ext_vector_type(8)));
typedef float  f32x4  __attribute__((ext_vector_type(4)));
typedef unsigned short u16x8 __attribute__((ext_vector_type(8)));

__device__ inline float bfu2f(unsigned short u) {
    union { unsigned int i; float f; } c; c.i = ((unsigned)u) << 16; return c.f;
}

// ===================== K0a: pack x -> channel-last bf16 with borders =====================
__global__ __launch_bounds__(256) void k_pack_x(const float* __restrict__ x,
                                                __hip_bfloat16* __restrict__ xp)
{
    const int bi  = blockIdx.x;          // 8*130
    const int b   = bi / 130;
    const int yp  = bi % 130;
    const int tid = threadIdx.x;
    const int y   = yp - 1;
    const bool interior = (y >= 0 && y < H);

    __shared__ float xs[CIN * W];
    if (interior) {
        for (int i = tid; i < CIN * W; i += 256)
            xs[i] = x[((size_t)b * CIN + (i >> 7)) * (H * W) + y * W + (i & 127)];
    }
    __syncthreads();
    __hip_bfloat16* op = xp + ((size_t)b * 130 + yp) * (130 * 72);
    for (int i = tid; i < 130 * 72; i += 256) {
        int xpx = i / 72, c = i - xpx * 72;
        int xx = xpx - 1;
        float v = 0.f;
        if (interior && xx >= 0 && xx < W && c < CIN) v = xs[c * W + xx];
        op[i] = __float2bfloat16(v);
    }
}

// ===================== K0b: ALL weight packs in one launch =====================
// blocks [0,256): conv3x3 w -> wp2 [3 ky][256 oc][232]
// blocks [256,1280): snake  -> wpk2 [8 l][9 k][128 oc][128 ic]  (ic-slot XOR-swizzled)
// blocks [1280,1536): fw    -> fwb  [256][1024]
// blocks [1536,1792): ppw1[:,256:] -> pw1hb [256][1024]
// blocks [1792,1856): ppw2  -> pw2b [64][256]
__global__ __launch_bounds__(256) void k_pack_weights(
    const float* __restrict__ w3, const float* __restrict__ hw,
    const float* __restrict__ rw, const float* __restrict__ fw,
    const float* __restrict__ ppw1, const float* __restrict__ ppw2,
    __hip_bfloat16* __restrict__ wp2, __hip_bfloat16* __restrict__ wpk2,
    __hip_bfloat16* __restrict__ fwb, __hip_bfloat16* __restrict__ pw1hb,
    __hip_bfloat16* __restrict__ pw2b)
{
    const int bid = blockIdx.x, tid = threadIdx.x;
    if (bid < 256) {
        int oc = bid;
        for (int t = tid; t < 3 * 232; t += 256) {
            int ky = t / 232, s = t - ky * 232;
            float v = 0.f;
            if (s < 216) {
                int kx = s / 72, ic = s - kx * 72;
                if (ic < CIN) v = w3[((size_t)(oc * CIN + ic) * 3 + ky) * 3 + kx];
            }
            wp2[((size_t)ky * 256 + oc) * 232 + s] = __float2bfloat16(v);
        }
    } else if (bid < 1280) {
        int q = bid - 256, l = q >> 7, oc = q & 127;
        for (int t = tid; t < 9 * 128; t += 256) {
            int k = t >> 7, ic = t & 127;
            float v = 0.f;
            if (l == 0) { if (ic < 66) v = hw[((size_t)oc * 66 + ic) * 9 + k]; }
            else v = rw[((((size_t)(l - 1) * 128 + oc) * 128) + ic) * 9 + k];
            // XOR-swizzle the 16B slot index within the row (T2; read undoes it)
            int s = ic >> 3, j = ic & 7;
            int sw = ((s ^ (oc & 7)) << 3) + j;
            wpk2[(((size_t)l * 9 + k) * 128 + oc) * 128 + sw] = __float2bfloat16(v);
        }
    } else if (bid < 1536) {
        int r = bid - 1280;
        for (int c = tid; c < 1024; c += 256)
            fwb[(size_t)r * 1024 + c] = __float2bfloat16(fw[(size_t)r * 1024 + c]);
    } else if (bid < 1792) {
        int r = bid - 1536;
        for (int c = tid; c < 1024; c += 256)
            pw1hb[(size_t)r * 1024 + c] = __float2bfloat16(ppw1[(size_t)r * 1280 + 256 + c]);
    } else {
        int r = bid - 1792;
        for (int c = tid; c < 256; c += 256)
            pw2b[(size_t)r * 256 + c] = __float2bfloat16(ppw2[(size_t)r * 256 + c]);
    }
}

// ===================== K1: 3x3 conv via implicit-GEMM MFMA (round-3 config) =====================
// grid (1024 = b*128+y, 2 ocg), block 256 = 4 waves (2M x 2N), wave 64 pos x 64 oc
// per-ky: stage A row (18720 B) + B tile (59392 B) -> 7 MFMA K-steps. 78 KB LDS, 2 blocks/CU.
__global__ __launch_bounds__(256, 2) void k_conv3x3_mfma(
    const __hip_bfloat16* __restrict__ xp,   // [8][130][130][72]
    const __hip_bfloat16* __restrict__ wp,   // [3][256][232]
    const float* __restrict__ bias,
    __hip_bfloat16* __restrict__ out)        // [8][128 y][128 x][256 oc]
{
    constexpr int SB = 232;
    __shared__ __hip_bfloat16 ash[9392];
    __shared__ __hip_bfloat16 bsh[128 * SB];

    const int tid = threadIdx.x;
    const int ln  = tid & 63;
    const int wv  = tid >> 6;
    const int wm  = (wv >> 1) * 64;
    const int wn  = (wv & 1) * 64;
    const int l15 = ln & 15;
    const int lhi = ln >> 4;

    const int by  = blockIdx.x;
    const int b   = by >> 7;
    const int y   = by & 127;
    const int ocb = blockIdx.y * 128;

    if (tid < 32) ash[9360 + tid] = __float2bfloat16(0.f);

    f32x4 acc[4][4] = {};

    for (int ky = 0; ky < 3; ++ky) {
        __syncthreads();
        {
            const char* g = (const char*)(xp + ((size_t)b * 130 + y + ky) * 9360);
            for (int off = wv * 1024; off < 18720; off += 4096) {
                int o = off + ln * 16;
                if (o < 18720)
                    __builtin_amdgcn_global_load_lds(
                        (const __attribute__((address_space(1))) void*)(g + o),
                        (__attribute__((address_space(3))) void*)((char*)ash + off),
                        16, 0, 0);
            }
        }
        {
            const char* g = (const char*)(wp + ((size_t)ky * 256 + ocb) * SB);
            for (int off = wv * 1024; off < 59392; off += 4096) {
                int o = off + ln * 16;
                if (o < 59392)
                    __builtin_amdgcn_global_load_lds(
                        (const __attribute__((address_space(1))) void*)(g + o),
                        (__attribute__((address_space(3))) void*)((char*)bsh + off),
                        16, 0, 0);
            }
        }
        __syncthreads();

#pragma unroll
        for (int ks = 0; ks < 7; ++ks) {
            bf16x8 a[4], bq[4];
#pragma unroll
            for (int m = 0; m < 4; ++m) {
                int pos = wm + m * 16 + l15;
                a[m] = *(const bf16x8*)((const char*)ash + pos * 144 + ks * 64 + lhi * 16);
            }
#pragma unroll
            for (int n = 0; n < 4; ++n) {
                int oc = wn + n * 16 + l15;
                bq[n] = *(const bf16x8*)((const char*)bsh + oc * (SB * 2) + ks * 64 + lhi * 16);
            }
#pragma unroll
            for (int m = 0; m < 4; ++m)
#pragma unroll
                for (int n = 0; n < 4; ++n)
                    acc[m][n] = __builtin_amdgcn_mfma_f32_16x16x32_bf16(
                        a[m], bq[n], acc[m][n], 0, 0, 0);
        }
    }

    // epilogue: bias + relu -> channel-last bf16
#pragma unroll
    for (int n = 0; n < 4; ++n) {
        int oc = ocb + wn + n * 16 + l15;
        float bb = bias[oc];
#pragma unroll
        for (int m = 0; m < 4; ++m) {
#pragma unroll
            for (int r = 0; r < 4; ++r) {
                int pos = wm + m * 16 + lhi * 4 + r;
                float v = acc[m][n][r] + bb;
                v = v > 0.f ? v : 0.f;
                out[(((size_t)b * 128 + y) * 128 + pos) * 256 + oc] = __float2bfloat16(v);
            }
        }
    }
}

// ===================== K2: 1x1 conv (256 -> 64) MFMA =====================
__global__ __launch_bounds__(256) void k_conv1x1_mfma(
    const __hip_bfloat16* __restrict__ feat1,   // [131072 pos][256]
    const __hip_bfloat16* __restrict__ w2b,     // [64][256]
    const float* __restrict__ b2,
    __hip_bfloat16* __restrict__ feat2)         // [131072 pos][64]
{
    const int tid = threadIdx.x;
    const int ln  = tid & 63;
    const int wv  = tid >> 6;
    const int wm  = wv * 64;
    const int l15 = ln & 15;
    const int lhi = ln >> 4;
    const int pos0 = blockIdx.x * 256;

    __shared__ __hip_bfloat16 wsh[64 * 136];
    for (int i = tid; i < 1024; i += 256) {
        int row = i >> 4, slot = i & 15;
        *(bf16x8*)&wsh[row * 136 + slot * 8] = *(const bf16x8*)(w2b + row * 256 + slot * 8);
    }
    __syncthreads();

    f32x4 acc[4][4] = {};
#pragma unroll
    for (int kk = 0; kk < 8; ++kk) {
        bf16x8 a[4], bq[4];
#pragma unroll
        for (int m = 0; m < 4; ++m)
            a[m] = *(const bf16x8*)(feat1 + (size_t)(pos0 + wm + m * 16 + l15) * 256 + kk * 32 + lhi * 8);
#pragma unroll
        for (int n = 0; n < 4; ++n)
            bq[n] = *(const bf16x8*)&wsh[(n * 16 + l15) * 136 + kk * 32 + lhi * 8];
#pragma unroll
        for (int m = 0; m < 4; ++m)
#pragma unroll
            for (int n = 0; n < 4; ++n)
                acc[m][n] = __builtin_amdgcn_mfma_f32_16x16x32_bf16(a[m], bq[n], acc[m][n], 0, 0, 0);
    }
#pragma unroll
    for (int n = 0; n < 4; ++n) {
        int og = n * 16 + l15;
        float bb = b2[og];
#pragma unroll
        for (int m = 0; m < 4; ++m)
#pragma unroll
            for (int r = 0; r < 4; ++r) {
                int pos = pos0 + wm + m * 16 + lhi * 4 + r;
                feat2[(size_t)pos * 64 + og] = __float2bfloat16(acc[m][n][r] + bb);
            }
    }
}

// ===================== K3: bilinear sample + coords -> X0 [p][v][128] bf16 =====================
__global__ __launch_bounds__(256) void k_sample(
    const __hip_bfloat16* __restrict__ feat2, const float* __restrict__ ipoly,
    const float* __restrict__ cpoly, const int* __restrict__ ind,
    __hip_bfloat16* __restrict__ X0)
{
    const int p = blockIdx.x;
    const int v = threadIdx.x & 127;
    const int half = threadIdx.x >> 7;

    float px = ipoly[(p * V + v) * 2 + 0];
    float py = ipoly[(p * V + v) * 2 + 1];
    float ix = px - 0.5f, iy = py - 0.5f;
    float x0f = floorf(ix), y0f = floorf(iy);
    float wx = ix - x0f, wy = iy - y0f;
    int x0 = (int)x0f, y0 = (int)y0f;

    int   xsv[2] = {x0, x0 + 1}, ysv[2] = {y0, y0 + 1};
    float wxs[2] = {1.f - wx, wx}, wys[2] = {1.f - wy, wy};
    float cw[4]; int cbase[4];
#pragma unroll
    for (int jy = 0; jy < 2; ++jy)
#pragma unroll
        for (int jx = 0; jx < 2; ++jx) {
            int xi = xsv[jx], yi = ysv[jy];
            bool ok = (xi >= 0) && (xi < W) && (yi >= 0) && (yi < H);
            int xc = min(max(xi, 0), W - 1);
            int yc = min(max(yi, 0), H - 1);
            cw[jy * 2 + jx]    = wys[jy] * wxs[jx] * (ok ? 1.f : 0.f);
            cbase[jy * 2 + jx] = yc * W + xc;
        }

    const __hip_bfloat16* fb = feat2 + (size_t)ind[p] * (16384 * 64);
    __hip_bfloat16* xr = X0 + ((size_t)p * V + v) * 128;
#pragma unroll
    for (int ch = 0; ch < 4; ++ch) {
        int chh = half * 4 + ch;
        float s[8];
#pragma unroll
        for (int e = 0; e < 8; ++e) s[e] = 0.f;
#pragma unroll
        for (int j = 0; j < 4; ++j) {
            u16x8 t = *(const u16x8*)(fb + (size_t)cbase[j] * 64 + chh * 8);
#pragma unroll
            for (int e = 0; e < 8; ++e) s[e] += cw[j] * bfu2f(t[e]);
        }
#pragma unroll
        for (int e = 0; e < 8; ++e) xr[chh * 8 + e] = __float2bfloat16(s[e]);
    }
    if (half) {
        xr[64] = __float2bfloat16(cpoly[(p * V + v) * 2 + 0] * RO);
        xr[65] = __float2bfloat16(cpoly[(p * V + v) * 2 + 1] * RO);
        for (int c = 66; c < 128; ++c) xr[c] = __float2bfloat16(0.f);
    }
}

// ===================== K4: snake circular conv layer (MFMA, 2-phase W pipeline) =====================
// grid (NP, 2 ocg), block 256 = 4 waves (2M x 2N), wave 64 pos x 32 oc.
// x staged once [128][136] (conflict-free 272B stride); W per-tap 16KB double-buffered,
// prefetch(tap+1) issued before compute(tap); W rows XOR-swizzled (pack pre-swizzles).
__global__ __launch_bounds__(256) void k_snake_mfma(
    const __hip_bfloat16* __restrict__ xin,   // [NP][V][128]
    const __hip_bfloat16* __restrict__ wl,    // [9][128 oc][128 ic] swizzled
    const float* __restrict__ bias, const float* __restrict__ gamma,
    const float* __restrict__ beta,
    const __hip_bfloat16* __restrict__ resin, // nullable, [NP][V][128]
    __hip_bfloat16* __restrict__ out,         // [NP][V][128]
    int dil)
{
    const int tid = threadIdx.x;
    const int ln  = tid & 63;
    const int wv  = tid >> 6;
    const int wm  = (wv >> 1) * 64;
    const int wn  = (wv & 1) * 32;
    const int l15 = ln & 15;
    const int lhi = ln >> 4;
    const int p   = blockIdx.x;
    const int ocb = blockIdx.y * 64;

    __shared__ __hip_bfloat16 xs[128 * 136];       // 34 KB
    __shared__ __hip_bfloat16 wsh[2 * 64 * 128];   // 2 x 16 KB

    // stage W tap 0 (16 KB contiguous)
    {
        const char* g = (const char*)(wl + (size_t)ocb * 128);
        for (int off = tid * 16; off < 16384; off += 4096)
            __builtin_amdgcn_global_load_lds(
                (const __attribute__((address_space(1))) void*)(g + off),
                (__attribute__((address_space(3))) void*)((char*)wsh + off), 16, 0, 0);
    }
    // stage x (one poly, 32 KB)
    const __hip_bfloat16* xb = xin + (size_t)p * (V * 128);
    for (int i = tid; i < 2048; i += 256) {
        int r = i >> 4, slot = i & 15;
        *(bf16x8*)&xs[r * 136 + slot * 8] = *(const bf16x8*)(xb + r * 128 + slot * 8);
    }
    __syncthreads();

    f32x4 acc[4][2] = {};
#pragma unroll 1
    for (int k = 0; k < 9; ++k) {
        // prefetch next tap's W into the other buffer (flies under compute)
        if (k < 8) {
            const char* g = (const char*)(wl + (size_t)(k + 1) * (128 * 128) + (size_t)ocb * 128);
            char* dst = (char*)wsh + ((k + 1) & 1) * 16384;
            for (int off = tid * 16; off < 16384; off += 4096)
                __builtin_amdgcn_global_load_lds(
                    (const __attribute__((address_space(1))) void*)(g + off),
                    (__attribute__((address_space(3))) void*)(dst + off), 16, 0, 0);
        }
        const __hip_bfloat16* wbuf = wsh + (k & 1) * 8192;
        const int ofs = (k - 4) * dil + 256;
#pragma unroll
        for (int kc = 0; kc < 4; ++kc) {
            bf16x8 a[4], bq[2];
#pragma unroll
            for (int m = 0; m < 4; ++m) {
                int row = (wm + m * 16 + l15 + ofs) & 127;
                a[m] = *(const bf16x8*)&xs[row * 136 + kc * 32 + lhi * 8];
            }
#pragma unroll
            for (int n = 0; n < 2; ++n) {
                int row  = wn + n * 16 + l15;
                int slot = (kc * 4 + lhi) ^ (row & 7);
                bq[n] = *(const bf16x8*)&wbuf[row * 128 + slot * 8];
            }
#pragma unroll
            for (int m = 0; m < 4; ++m)
#pragma unroll
                for (int n = 0; n < 2; ++n)
                    acc[m][n] = __builtin_amdgcn_mfma_f32_16x16x32_bf16(a[m], bq[n], acc[m][n], 0, 0, 0);
        }
        __syncthreads();
    }

#pragma unroll
    for (int n = 0; n < 2; ++n) {
        int oc = ocb + wn + n * 16 + l15;
        float bb = bias[oc], gg = gamma[oc], bt = beta[oc];
#pragma unroll
        for (int m = 0; m < 4; ++m)
#pragma unroll
            for (int r = 0; r < 4; ++r) {
                int pos = wm + m * 16 + lhi * 4 + r;
                size_t idx = ((size_t)p * V + pos) * 128 + oc;
                float v = acc[m][n][r] + bb;
                v = v > 0.f ? v : 0.f;
                v = v * gg + bt;
                if (resin) v += __bfloat162float(resin[idx]);
                out[idx] = __float2bfloat16(v);
            }
    }
}

// ===================== K5: vconv over concat states (K=1024, O=256) =====================
__global__ __launch_bounds__(256) void k_vconv1024(
    const __hip_bfloat16* __restrict__ xin,   // states [8][NP][V][128]
    const __hip_bfloat16* __restrict__ wb,    // [256][1024]
    const float* __restrict__ fbias,          // nullable [256]
    const float* __restrict__ pbias,          // nullable [NP][256]
    int relu,
    __hip_bfloat16* __restrict__ out)         // [NP][V][256]
{
    const int tid = threadIdx.x;
    const int ln  = tid & 63;
    const int wv  = tid >> 6;
    const int wm  = (wv >> 1) * 64;
    const int wn  = (wv & 1) * 64;
    const int l15 = ln & 15;
    const int lhi = ln >> 4;
    const int p   = blockIdx.x;
    const int ocb = blockIdx.y * 128;

    f32x4 acc[4][4] = {};
    for (int s = 0; s < 8; ++s) {
        const __hip_bfloat16* xa = xin + ((size_t)s * NP + p) * (V * 128);
#pragma unroll
        for (int kc = 0; kc < 4; ++kc) {
            bf16x8 a[4], bq[4];
#pragma unroll
            for (int m = 0; m < 4; ++m)
                a[m] = *(const bf16x8*)(xa + (size_t)(wm + m * 16 + l15) * 128 + kc * 32 + lhi * 8);
#pragma unroll
            for (int n = 0; n < 4; ++n)
                bq[n] = *(const bf16x8*)(wb + (size_t)(ocb + wn + n * 16 + l15) * 1024 + s * 128 + kc * 32 + lhi * 8);
#pragma unroll
            for (int m = 0; m < 4; ++m)
#pragma unroll
                for (int n = 0; n < 4; ++n)
                    acc[m][n] = __builtin_amdgcn_mfma_f32_16x16x32_bf16(a[m], bq[n], acc[m][n], 0, 0, 0);
        }
    }
#pragma unroll
    for (int n = 0; n < 4; ++n) {
        int og = ocb + wn + n * 16 + l15;
        float bb = (fbias ? fbias[og] : 0.f) + (pbias ? pbias[(size_t)p * 256 + og] : 0.f);
#pragma unroll
        for (int m = 0; m < 4; ++m)
#pragma unroll
            for (int r = 0; r < 4; ++r) {
                int pos = wm + m * 16 + lhi * 4 + r;
                float v = acc[m][n][r] + bb;
                if (relu) v = v > 0.f ? v : 0.f;
                out[((size_t)p * V + pos) * 256 + og] = __float2bfloat16(v);
            }
    }
}

// ===================== K6: h2 = relu(pw2 @ h1 + pb2)  (K=256, O=64) =====================
__global__ __launch_bounds__(128) void k_h2(
    const __hip_bfloat16* __restrict__ h1,    // [NP][V][256]
    const __hip_bfloat16* __restrict__ w2b,   // [64][256]
    const float* __restrict__ pb2,
    __hip_bfloat16* __restrict__ h2)          // [NP][V][64]
{
    const int tid = threadIdx.x;
    const int ln  = tid & 63;
    const int wv  = tid >> 6;
    const int wm  = wv * 64;
    const int l15 = ln & 15;
    const int lhi = ln >> 4;
    const int p   = blockIdx.x;

    f32x4 acc[4][4] = {};
#pragma unroll
    for (int kk = 0; kk < 8; ++kk) {
        bf16x8 a[4], bq[4];
#pragma unroll
        for (int m = 0; m < 4; ++m)
            a[m] = *(const bf16x8*)(h1 + ((size_t)p * V + wm + m * 16 + l15) * 256 + kk * 32 + lhi * 8);
#pragma unroll
        for (int n = 0; n < 4; ++n)
            bq[n] = *(const bf16x8*)(w2b + (size_t)(n * 16 + l15) * 256 + kk * 32 + lhi * 8);
#pragma unroll
        for (int m = 0; m < 4; ++m)
#pragma unroll
            for (int n = 0; n < 4; ++n)
                acc[m][n] = __builtin_amdgcn_mfma_f32_16x16x32_bf16(a[m], bq[n], acc[m][n], 0, 0, 0);
    }
#pragma unroll
    for (int n = 0; n < 4; ++n) {
        int og = n * 16 + l15;
        float bb = pb2[og];
#pragma unroll
        for (int m = 0; m < 4; ++m)
#pragma unroll
            for (int r = 0; r < 4; ++r) {
                int pos = wm + m * 16 + lhi * 4 + r;
                float v = acc[m][n][r] + bb;
                v = v > 0.f ? v : 0.f;
                h2[((size_t)p * V + pos) * 64 + og] = __float2bfloat16(v);
            }
    }
}

// ===================== K7: fused g = max_v(fused), gc = pb1 + pw1[:, :256] . g =====================
__global__ __launch_bounds__(256) void k_gmaxgc(const __hip_bfloat16* __restrict__ fused,
                                                const float* __restrict__ pw1,
                                                const float* __restrict__ pb1,
                                                float* __restrict__ gc)
{
    int p = blockIdx.x, o = threadIdx.x;
    float m = -3.4e38f;
    for (int v = 0; v < V; ++v)
        m = fmaxf(m, __bfloat162float(fused[((size_t)p * V + v) * 256 + o]));
    __shared__ float gl[256];
    gl[o] = m;
    __syncthreads();
    float a = pb1[o];
    const float* wr = pw1 + (size_t)o * 1280;
    for (int c = 0; c < 256; ++c) a += wr[c] * gl[c];
    gc[(size_t)p * 256 + o] = a;
}

// ===================== K8: final pw3 + compose output =====================
__global__ __launch_bounds__(128) void k_final(const __hip_bfloat16* __restrict__ h2,
                                               const float* __restrict__ pw3,
                                               const float* __restrict__ pb3,
                                               const float* __restrict__ ipoly,
                                               float* __restrict__ outp)
{
    int p = blockIdx.x, v = threadIdx.x;
    __shared__ float w3[128];
    w3[v] = pw3[v];
    __syncthreads();
    float a0 = pb3[0], a1 = pb3[1];
    const u16x8* hp = (const u16x8*)(h2 + ((size_t)p * V + v) * 64);
#pragma unroll
    for (int ch = 0; ch < 8; ++ch) {
        u16x8 t = hp[ch];
#pragma unroll
        for (int e = 0; e < 8; ++e) {
            int c = ch * 8 + e;
            float hv = bfu2f(t[e]);
            a0 += w3[c] * hv;
            a1 += w3[64 + c] * hv;
        }
    }
    int idx = (p * V + v) * 2;
    outp[idx]     = ipoly[idx] * RO + a0;
    outp[idx + 1] = ipoly[idx + 1] * RO + a1;
}

// ===================== host =====================
extern "C" void kernel_launch(void* const* d_in, const int* in_sizes, int n_in,
                              void* d_out, int out_size, void* d_ws, size_t ws_size,
                              hipStream_t stream)
{
    const float* cnn   = (const float*)d_in[0];
    const float* ipoly = (const float*)d_in[1];
    const float* cpoly = (const float*)d_in[2];
    const int*   ind   = (const int*)d_in[3];
    const float* pw1c  = (const float*)d_in[4];
    const float* pb1c  = (const float*)d_in[5];
    const float* pw2c  = (const float*)d_in[6];
    const float* pb2c  = (const float*)d_in[7];
    const float* hw    = (const float*)d_in[8];
    const float* hb    = (const float*)d_in[9];
    const float* hg    = (const float*)d_in[10];
    const float* hbt   = (const float*)d_in[11];
    const float* rw    = (const float*)d_in[12];
    const float* rb    = (const float*)d_in[13];
    const float* rg    = (const float*)d_in[14];
    const float* rbt   = (const float*)d_in[15];
    const float* fw    = (const float*)d_in[16];
    const float* fb    = (const float*)d_in[17];
    const float* ppw1  = (const float*)d_in[18];
    const float* ppb1  = (const float*)d_in[19];
    const float* ppw2  = (const float*)d_in[20];
    const float* ppb2  = (const float*)d_in[21];
    const float* ppw3  = (const float*)d_in[22];
    const float* ppb3  = (const float*)d_in[23];
    float* outp = (float*)d_out;

    char* ws = (char*)d_ws;
    __hip_bfloat16* feat1  = (__hip_bfloat16*)(ws);
    __hip_bfloat16* states = (__hip_bfloat16*)(ws);
    __hip_bfloat16* fused  = (__hip_bfloat16*)(ws + 33554432);
    __hip_bfloat16* h1     = (__hip_bfloat16*)(ws + 41943040);
    __hip_bfloat16* h2     = (__hip_bfloat16*)(ws + 50331648);
    float*          gcbuf  = (float*)(ws + 52428800);
    __hip_bfloat16* xp     = (__hip_bfloat16*)(ws + 67108864);
    __hip_bfloat16* feat2  = (__hip_bfloat16*)(ws + 67108864);
    __hip_bfloat16* wp2    = (__hip_bfloat16*)(ws + 86577664);
    __hip_bfloat16* wpk2   = (__hip_bfloat16*)(ws + 86934016);
    __hip_bfloat16* fwb    = (__hip_bfloat16*)(ws + 89293312);
    __hip_bfloat16* pw1hb  = (__hip_bfloat16*)(ws + 89817600);
    __hip_bfloat16* pw2b   = (__hip_bfloat16*)(ws + 90341888);
    __hip_bfloat16* X0     = (__hip_bfloat16*)(ws + 90374656);

    // 0) packs
    k_pack_x<<<dim3(8 * 130), 256, 0, stream>>>(cnn, xp);
    k_pack_weights<<<dim3(1856), 256, 0, stream>>>(pw1c, hw, rw, fw, ppw1, ppw2,
                                                   wp2, wpk2, fwb, pw1hb, pw2b);

    // 1) 3x3 conv + relu -> feat1 (channel-last bf16)
    k_conv3x3_mfma<<<dim3(1024, 2), 256, 0, stream>>>(xp, wp2, pb1c, feat1);
    // 2) 1x1 conv -> feat2 (channel-last bf16)
    k_conv1x1_mfma<<<dim3(512), 256, 0, stream>>>(feat1, pw2b, pb2c, feat2);
    // 3) bilinear sample + coords -> X0 [p][v][128] bf16
    k_sample<<<dim3(NP), 256, 0, stream>>>(feat2, ipoly, cpoly, ind, X0);

    // 4) head conv -> states[0]
    k_snake_mfma<<<dim3(NP, 2), 256, 0, stream>>>(X0, wpk2, hb, hg, hbt, nullptr,
                                                  states, 1);
    // 5..11) residual dilated convs
    const int dil[NRES] = {1, 1, 1, 2, 2, 4, 4};
    const size_t SSZ = (size_t)NP * V * 128;
    for (int i = 0; i < NRES; ++i) {
        const __hip_bfloat16* xin = states + (size_t)i * SSZ;
        __hip_bfloat16* yout      = states + (size_t)(i + 1) * SSZ;
        const __hip_bfloat16* wi  = wpk2 + (size_t)(i + 1) * 9 * 128 * 128;
        k_snake_mfma<<<dim3(NP, 2), 256, 0, stream>>>(xin, wi, rb + i * SD, rg + i * SD,
                                                      rbt + i * SD, xin, yout, dil[i]);
    }

    // 12) fused 1x1 over concat states -> fused [p][v][256]
    k_vconv1024<<<dim3(NP, 2), 256, 0, stream>>>(states, fwb, fb, nullptr, 0, fused);
    // 13+14) g = max over vertices ; gc = pb1 + pw1[:, :256] @ g
    k_gmaxgc<<<dim3(NP), 256, 0, stream>>>(fused, ppw1, ppb1, gcbuf);
    // 15) h1 = relu(pw1[:, 256:] @ state + gc)
    k_vconv1024<<<dim3(NP, 2), 256, 0, stream>>>(states, pw1hb, nullptr, gcbuf, 1, h1);
    // 16) h2 = relu(pw2 @ h1 + pb2)
    k_h2<<<dim3(NP), 128, 0, stream>>>(h1, pw2b, ppb2, h2);
    // 17) final
    k_final<<<dim3(NP), 128, 0, stream>>>(h2, ppw3, ppb3, ipoly, outp);
}